// Round 3
// baseline (1271.958 us; speedup 1.0000x reference)
//
#include <hip/hip_runtime.h>
#include <hip/hip_bf16.h>

#define NN 100000
#define EE 640000
#define DD 128
#define RR 8
#define K8 (NN * RR)      // 800000 (rel,dst) pair keys, key = r*NN + dst
#define NSB2 196          // ceil(K8/4096)
#define NB 1563           // ceil(NN/64) gemm_agg blocks

typedef __attribute__((ext_vector_type(8))) short short8;
typedef __attribute__((ext_vector_type(4))) float floatx4;
typedef __attribute__((ext_vector_type(4))) unsigned int uint4v;

__device__ __forceinline__ unsigned short f2bf(float f) {
  unsigned int u = __float_as_uint(f);
  u += 0x7FFFu + ((u >> 16) & 1u);   // RNE
  return (unsigned short)(u >> 16);
}
__device__ __forceinline__ unsigned int pk2bf(float a, float b) {
  __hip_bfloat162 h = __float22bfloat162_rn(make_float2(a, b));
  unsigned int u;
  __builtin_memcpy(&u, &h, 4);
  return u;                          // low16 = a, high16 = b
}
__device__ __forceinline__ float bflo(unsigned int u) { return __uint_as_float(u << 16); }
__device__ __forceinline__ float bfhi(unsigned int u) { return __uint_as_float(u & 0xFFFF0000u); }

// ---------------------------------------------------------------------------
// x (fp32 [NN][128]) -> Xb (bf16 std rows as uints: uint j = cols 2j|2j+1<<16)
// ---------------------------------------------------------------------------
__global__ __launch_bounds__(256) void xb_prep(
    const float* __restrict__ x, unsigned int* __restrict__ xb)
{
  int g = blockIdx.x * 256 + threadIdx.x;
  int v = g >> 4, seg = g & 15;
  const float4* s4 = (const float4*)(x + (size_t)v * 128 + seg * 8);
  float4 a = s4[0], b = s4[1];
  uint4v o;
  o[0] = pk2bf(a.x, a.y); o[1] = pk2bf(a.z, a.w);
  o[2] = pk2bf(b.x, b.y); o[3] = pk2bf(b.z, b.w);
  *(uint4v*)(xb + (size_t)v * 64 + seg * 4) = o;
}

// ---------------------------------------------------------------------------
// Weights: wt[set][r][n][k] = bf16(W[kk][n]); r=8 is root. Set 1 permutes k
// to match layer-1's packed epilogue layout.
// ---------------------------------------------------------------------------
__global__ __launch_bounds__(256) void w_prep_all(
    const float* __restrict__ rel1, const float* __restrict__ root1,
    const float* __restrict__ rel2, const float* __restrict__ root2,
    unsigned short* __restrict__ wt)
{
  int id = blockIdx.x * 256 + threadIdx.x;       // [0, 2*9*16384)
  int set = id >= 147456;
  int rem = id - set * 147456;
  int r = rem >> 14, n = (rem >> 7) & 127, k = rem & 127;
  int kk = k;
  if (set) {
    int u = k >> 1, w2 = u >> 4, m2 = u & 15;
    kk = w2 * 32 + m2 + ((k & 1) << 4);
  }
  const float* rel = set ? rel2 : rel1;
  const float* root = set ? root2 : root1;
  float v = (r < RR) ? rel[((size_t)r * DD + kk) * DD + n] : root[(size_t)kk * DD + n];
  wt[id] = f2bf(v);
}

// ---------------------------------------------------------------------------
// One atomic per edge; return value = rank in (r,dst) segment.
// ---------------------------------------------------------------------------
__global__ __launch_bounds__(256) void count_all(
    const int* __restrict__ ei, const int* __restrict__ et,
    int* __restrict__ cnt, int* __restrict__ erank)
{
  int e = blockIdx.x * 256 + threadIdx.x;
  int dst = ei[EE + e], r = et[e];
  erank[e] = atomicAdd(&cnt[r * NN + dst], 1);
}

// ---------------------------------------------------------------------------
// 3-phase exclusive scan over cnt[K8] -> rowptr[K8+1].
// ---------------------------------------------------------------------------
__global__ __launch_bounds__(256) void scan_a(
    const int4* __restrict__ c4, int n4, int* __restrict__ bsum)
{
  int t = threadIdx.x;
  int s = 0;
#pragma unroll
  for (int i = 0; i < 4; ++i) {
    int idx = blockIdx.x * 1024 + i * 256 + t;
    if (idx < n4) { int4 v = c4[idx]; s += v.x + v.y + v.z + v.w; }
  }
  __shared__ int wsum[4];
  for (int d = 32; d; d >>= 1) s += __shfl_xor(s, d, 64);
  if ((t & 63) == 0) wsum[t >> 6] = s;
  __syncthreads();
  if (t == 0) bsum[blockIdx.x] = wsum[0] + wsum[1] + wsum[2] + wsum[3];
}

__global__ void scan_b(const int* __restrict__ bsum, int nsb,
                       int* __restrict__ bbase)
{
  int lane = threadIdx.x;                         // 64 threads
  int v[4]; int s = 0;
#pragma unroll
  for (int i = 0; i < 4; ++i) {
    int idx = lane * 4 + i;
    v[i] = (idx < nsb) ? bsum[idx] : 0; s += v[i];
  }
  int inc = s;
  for (int d = 1; d < 64; d <<= 1) {
    int o = __shfl_up(inc, d, 64);
    if (lane >= d) inc += o;
  }
  int running = inc - s;
#pragma unroll
  for (int i = 0; i < 4; ++i) {
    int idx = lane * 4 + i;
    if (idx < nsb) { bbase[idx] = running; running += v[i]; }
  }
}

__global__ __launch_bounds__(256) void scan_c(
    const int* __restrict__ cnt, const int* __restrict__ bbase, int n,
    int* __restrict__ out0)
{
  int t = threadIdx.x;
  int base = blockIdx.x * 4096 + t * 16;
  int v[16]; int s = 0;
#pragma unroll
  for (int i = 0; i < 16; ++i) {
    int idx = base + i;
    v[i] = (idx < n) ? cnt[idx] : 0;
    s += v[i];
  }
  int lane = t & 63, wid = t >> 6;
  int inc = s;
  for (int d = 1; d < 64; d <<= 1) {
    int o = __shfl_up(inc, d, 64);
    if (lane >= d) inc += o;
  }
  __shared__ int wsum[4];
  if (lane == 63) wsum[wid] = inc;
  __syncthreads();
  int wb = 0;
  for (int w = 0; w < wid; ++w) wb += wsum[w];
  int running = bbase[blockIdx.x] + wb + (inc - s);
#pragma unroll
  for (int i = 0; i < 16; ++i) {
    int idx = base + i;
    if (idx < n) { out0[idx] = running; running += v[i]; }
  }
  if (blockIdx.x == 0 && t == 0) out0[n] = EE;
}

// ---------------------------------------------------------------------------
// Place edges into (r,dst)-major CSR, no atomics. rec packs src (bits 0-19)
// and dst-in-64-block (bits 20-25): consumer block v0 is 64-aligned.
// ---------------------------------------------------------------------------
__global__ __launch_bounds__(256) void place(
    const int* __restrict__ ei, const int* __restrict__ et,
    const int* __restrict__ rowptr, const int* __restrict__ erank,
    int* __restrict__ recs)
{
  int e = blockIdx.x * 256 + threadIdx.x;
  int src = ei[e], dst = ei[EE + e], r = et[e];
  recs[rowptr[r * NN + dst] + erank[e]] = src | ((dst & 63) << 20);
}

// ---------------------------------------------------------------------------
// Fused aggregate-then-GEMM, edge-parallel. Block owns 64 dst rows.
// Per relation: edges of the block's contiguous CSR span are processed
// 8-lanes-per-edge, 32 edges in flight; lanes atomicAdd their 16 f32 values
// into a padded LDS accumulator (no dependency chains). Convert phase scales
// by 1/cnt, packs bf16 into the rotated A-tile, zeroes accum. One MFMA round
// per relation accumulates into registers; epilogue = bias + ReLU + store.
// ---------------------------------------------------------------------------
__global__ __launch_bounds__(256, 3) void gemm_agg(
    const unsigned int* __restrict__ Xb,     // [NN][64] packed bf16 rows
    const unsigned short* __restrict__ Wt,   // [9][128][128] bf16 [r][n][k]
    const int* __restrict__ rowptr,          // [K8+1]
    const int* __restrict__ recs,            // [EE] packed (src, d6)
    const float* __restrict__ bias,          // [128]
    void* __restrict__ outp, int out_bf16)
{
  const int v0 = blockIdx.x * 64;
  __shared__ __align__(16) unsigned short As[64 * 128];  // 16 KB
  __shared__ __align__(16) float Accum[64 * 132];        // 33 KB (pad 132)
  __shared__ int Rp[8 * 65 + 8];

  const int tid = threadIdx.x;
  const int wave = tid >> 6, lane = tid & 63;
  const int quad = lane >> 4, mr = lane & 15;
  const int li = tid & 7;          // lane-in-edge (32B slice)
  const int e8 = (tid >> 3) & 7;   // edge-slot within wave (bank stagger)
  const uint4v* Xb4 = (const uint4v*)Xb;
  unsigned int* Asu = (unsigned int*)As;

  // Rp[r*65 + j] = rowptr[r*NN + min(v0+j, NN)]  (clamp: last block's span
  // must not bleed into relation r+1)
  for (int id = tid; id < 520; id += 256) {
    int r = id / 65, j = id - r * 65;
    Rp[id] = rowptr[r * NN + min(v0 + j, NN)];
  }
  for (int i = tid; i < 64 * 132; i += 256) Accum[i] = 0.f;

  floatx4 acc[4][2];
#pragma unroll
  for (int mi = 0; mi < 4; ++mi) {
    acc[mi][0] = (floatx4){0.f, 0.f, 0.f, 0.f};
    acc[mi][1] = (floatx4){0.f, 0.f, 0.f, 0.f};
  }
  __syncthreads();

  // ---- edge-parallel accumulate of relation rn into Accum ----
  auto ACCUM_REL = [&](int rn) {
    int B = Rp[rn * 65], E = Rp[rn * 65 + 64];
    for (int e = B + (tid >> 3); e < E; e += 32) {
      int rec = recs[e];
      int src = rec & 0xFFFFF;
      int d = rec >> 20;
      const uint4v* xp = Xb4 + (size_t)src * 16 + li * 2;
      uint4v u0 = xp[0], u1 = xp[1];
      unsigned um[8];
      *(uint4v*)&um[0] = u0; *(uint4v*)&um[4] = u1;
      float* ac = &Accum[d * 132 + li * 16];
#pragma unroll
      for (int j = 0; j < 8; ++j) {
        int m = (j + e8) & 7;
        atomicAdd(&ac[2 * m], bflo(um[m]));
        atomicAdd(&ac[2 * m + 1], bfhi(um[m]));
      }
    }
  };

  // ---- Accum -> As (scaled bf16, rotated), zero Accum ----
  auto CONVERT_REL = [&](int rn) {
    int d = tid >> 2, q = tid & 3;
    int cnt = Rp[rn * 65 + d + 1] - Rp[rn * 65 + d];
    float sc = 1.0f / (float)max(cnt, 1);
    int rot = (d & 15) * 4;
    float* ac = &Accum[d * 132 + q * 32];
    uint4v o[4];
#pragma unroll
    for (int c = 0; c < 4; ++c) {
      float4 f0 = *(float4*)&ac[c * 8];
      float4 f1 = *(float4*)&ac[c * 8 + 4];
      o[c][0] = pk2bf(f0.x * sc, f0.y * sc);
      o[c][1] = pk2bf(f0.z * sc, f0.w * sc);
      o[c][2] = pk2bf(f1.x * sc, f1.y * sc);
      o[c][3] = pk2bf(f1.z * sc, f1.w * sc);
    }
#pragma unroll
    for (int c = 0; c < 4; ++c) {
      *(uint4v*)&Asu[d * 64 + ((q * 16 + c * 4 + rot) & 63)] = o[c];
      *(float4*)&ac[c * 8] = make_float4(0.f, 0.f, 0.f, 0.f);
      *(float4*)&ac[c * 8 + 4] = make_float4(0.f, 0.f, 0.f, 0.f);
    }
  };

  // ---- stage root rows (raw packed uints) into Accum; then copy to As ----
  auto STAGE_ROOT = [&]() {
    int row = tid >> 2, q4 = tid & 3;
    int v = v0 + row;
    int src = (v < NN) ? v : 0;
    const uint4v* xs = Xb4 + (size_t)src * 16 + q4 * 4;
    unsigned* au = (unsigned*)Accum;
#pragma unroll
    for (int c = 0; c < 4; ++c) {
      uint4v vv = xs[c];
      *(uint4v*)&au[row * 132 + q4 * 16 + c * 4] = vv;
    }
  };
  auto CONVERT_ROOT = [&]() {
    int d = tid >> 2, q = tid & 3;
    int rot = (d & 15) * 4;
    unsigned* au = (unsigned*)Accum;
#pragma unroll
    for (int c = 0; c < 4; ++c) {
      uint4v vv = *(uint4v*)&au[d * 132 + q * 16 + c * 4];
      *(uint4v*)&Asu[d * 64 + ((q * 16 + c * 4 + rot) & 63)] = vv;
    }
  };

  // prologue: build relation-0 A-tile
  ACCUM_REL(0);
  __syncthreads();
  CONVERT_REL(0);
  __syncthreads();

#pragma unroll 1
  for (int r = 0; r < 9; ++r) {
    // B fragments for W_r (global, L2-resident)
    const unsigned short* wr =
        Wt + (size_t)r * 16384 + (size_t)(wave * 32 + mr) * 128 + quad * 8;
    short8 b0[4], b1[4];
#pragma unroll
    for (int ks = 0; ks < 4; ++ks) {
      b0[ks] = *(const short8*)(wr + ks * 32);
      b1[ks] = *(const short8*)(wr + 16 * 128 + ks * 32);
    }
    // MFMA round on current As (relation r)
#pragma unroll
    for (int ks = 0; ks < 4; ++ks) {
      short8 a[4];
#pragma unroll
      for (int mi = 0; mi < 4; ++mi)
        a[mi] = *(const short8*)&As[(mi * 16 + mr) * 128 +
                                    ((ks * 32 + quad * 8 + mr * 8) & 127)];
#pragma unroll
      for (int mi = 0; mi < 4; ++mi) {
        acc[mi][0] = __builtin_amdgcn_mfma_f32_16x16x32_bf16(a[mi], b0[ks], acc[mi][0], 0, 0, 0);
        acc[mi][1] = __builtin_amdgcn_mfma_f32_16x16x32_bf16(a[mi], b1[ks], acc[mi][1], 0, 0, 0);
      }
    }
    // produce next A-tile (overlaps MFMA across waves)
    if (r < 7) ACCUM_REL(r + 1);
    else if (r == 7) STAGE_ROOT();
    __syncthreads();
    if (r < 7) CONVERT_REL(r + 1);
    else if (r == 7) CONVERT_ROOT();
    __syncthreads();
  }

  // ---- epilogue: bias + ReLU, direct store ----
  float bia0 = bias[wave * 32 + mr], bia1 = bias[wave * 32 + 16 + mr];
#pragma unroll
  for (int mi = 0; mi < 4; ++mi)
#pragma unroll
    for (int rg = 0; rg < 4; ++rg) {
      int row = mi * 16 + quad * 4 + rg;
      int v = v0 + row;
      if (v < NN) {
        float c0 = fmaxf(acc[mi][0][rg] + bia0, 0.f);
        float c1 = fmaxf(acc[mi][1][rg] + bia1, 0.f);
        if (out_bf16) {
          ((unsigned int*)outp)[(size_t)v * 64 + wave * 16 + mr] = pk2bf(c0, c1);
        } else {
          float* o = (float*)outp;
          o[(size_t)v * 128 + wave * 32 + mr] = c0;
          o[(size_t)v * 128 + wave * 32 + 16 + mr] = c1;
        }
      }
    }
}

// ---------------------------------------------------------------------------
extern "C" void kernel_launch(void* const* d_in, const int* in_sizes, int n_in,
                              void* d_out, int out_size, void* d_ws, size_t ws_size,
                              hipStream_t stream) {
  const float* x       = (const float*)d_in[0];
  const int*   ei      = (const int*)d_in[1];
  const int*   et      = (const int*)d_in[2];
  const float* rel_w1  = (const float*)d_in[3];
  const float* root_w1 = (const float*)d_in[4];
  const float* b1      = (const float*)d_in[5];
  const float* rel_w2  = (const float*)d_in[6];
  const float* root_w2 = (const float*)d_in[7];
  const float* b2      = (const float*)d_in[8];

  char* ws = (char*)d_ws;
  size_t off = 0;
  auto alloc = [&](size_t bytes) { char* p = ws + off; off = (off + bytes + 255) & ~(size_t)255; return p; };
  unsigned int*   Xb    = (unsigned int*)alloc((size_t)NN * 64 * 4);         // 25.6 MB
  unsigned int*   h1    = (unsigned int*)alloc((size_t)NN * 64 * 4);         // 25.6 MB (permuted pack)
  unsigned short* Wt    = (unsigned short*)alloc((size_t)2 * 9 * DD * DD * 2);
  int*            cnt   = (int*)alloc((size_t)K8 * 4);                       // 3.2 MB (zeroed)
  int*            rowptr= (int*)alloc((size_t)(K8 + 1) * 4);                 // 3.2 MB
  int*            erank = (int*)alloc((size_t)EE * 4);                       // 2.56 MB
  int*            recs  = (int*)alloc((size_t)EE * 4);                       // 2.56 MB
  int*            bsum  = (int*)alloc((size_t)NSB2 * 4);
  int*            bbase = (int*)alloc((size_t)NSB2 * 4);

  hipMemsetAsync(cnt, 0, (size_t)K8 * 4, stream);

  xb_prep<<<(NN * 16) / 256, 256, 0, stream>>>(x, Xb);
  w_prep_all<<<(2 * 9 * DD * DD) / 256, 256, 0, stream>>>(rel_w1, root_w1, rel_w2, root_w2, Wt);
  count_all<<<EE / 256, 256, 0, stream>>>(ei, et, cnt, erank);

  scan_a<<<NSB2, 256, 0, stream>>>((const int4*)cnt, K8 / 4, bsum);
  scan_b<<<1, 64, 0, stream>>>(bsum, NSB2, bbase);
  scan_c<<<NSB2, 256, 0, stream>>>(cnt, bbase, K8, rowptr);

  place<<<EE / 256, 256, 0, stream>>>(ei, et, rowptr, erank, recs);

  gemm_agg<<<NB, 256, 0, stream>>>(Xb, Wt, rowptr, recs, b1, h1, 1);
  gemm_agg<<<NB, 256, 0, stream>>>(h1, Wt + (size_t)9 * DD * DD, rowptr, recs, b2, d_out, 0);
}

// Round 4
// 504.677 us; speedup vs baseline: 2.5203x; 2.5203x over previous
//
#include <hip/hip_runtime.h>
#include <hip/hip_bf16.h>

#define NN 100000
#define EE 640000
#define DD 128
#define RR 8
#define K8 (NN * RR)      // 800000 (rel,dst) pair keys, key = r*NN + dst
#define NSB2 196          // ceil(K8/4096)
#define NB 1563           // ceil(NN/64) gemm_agg blocks

typedef __attribute__((ext_vector_type(8))) short short8;
typedef __attribute__((ext_vector_type(4))) float floatx4;
typedef __attribute__((ext_vector_type(4))) unsigned int uint4v;

__device__ __forceinline__ unsigned short f2bf(float f) {
  unsigned int u = __float_as_uint(f);
  u += 0x7FFFu + ((u >> 16) & 1u);   // RNE
  return (unsigned short)(u >> 16);
}
__device__ __forceinline__ unsigned int pk2bf(float a, float b) {
  __hip_bfloat162 h = __float22bfloat162_rn(make_float2(a, b));
  unsigned int u;
  __builtin_memcpy(&u, &h, 4);
  return u;                          // low16 = a, high16 = b
}
__device__ __forceinline__ float bflo(unsigned int u) { return __uint_as_float(u << 16); }
__device__ __forceinline__ float bfhi(unsigned int u) { return __uint_as_float(u & 0xFFFF0000u); }

// ---------------------------------------------------------------------------
// x (fp32 [NN][128]) -> Xb (bf16 std rows as uints: uint j = cols 2j|2j+1<<16)
// ---------------------------------------------------------------------------
__global__ __launch_bounds__(256) void xb_prep(
    const float* __restrict__ x, unsigned int* __restrict__ xb)
{
  int g = blockIdx.x * 256 + threadIdx.x;
  int v = g >> 4, seg = g & 15;
  const float4* s4 = (const float4*)(x + (size_t)v * 128 + seg * 8);
  float4 a = s4[0], b = s4[1];
  uint4v o;
  o[0] = pk2bf(a.x, a.y); o[1] = pk2bf(a.z, a.w);
  o[2] = pk2bf(b.x, b.y); o[3] = pk2bf(b.z, b.w);
  *(uint4v*)(xb + (size_t)v * 64 + seg * 4) = o;
}

// ---------------------------------------------------------------------------
// Weights: wt[set][r][n][k] = bf16(W[kk][n]); r=8 is root. Set 1 permutes k
// to match layer-1's packed epilogue layout.
// ---------------------------------------------------------------------------
__global__ __launch_bounds__(256) void w_prep_all(
    const float* __restrict__ rel1, const float* __restrict__ root1,
    const float* __restrict__ rel2, const float* __restrict__ root2,
    unsigned short* __restrict__ wt)
{
  int id = blockIdx.x * 256 + threadIdx.x;       // [0, 2*9*16384)
  int set = id >= 147456;
  int rem = id - set * 147456;
  int r = rem >> 14, n = (rem >> 7) & 127, k = rem & 127;
  int kk = k;
  if (set) {
    int u = k >> 1, w2 = u >> 4, m2 = u & 15;
    kk = w2 * 32 + m2 + ((k & 1) << 4);
  }
  const float* rel = set ? rel2 : rel1;
  const float* root = set ? root2 : root1;
  float v = (r < RR) ? rel[((size_t)r * DD + kk) * DD + n] : root[(size_t)kk * DD + n];
  wt[id] = f2bf(v);
}

// ---------------------------------------------------------------------------
// One atomic per edge; return value = rank in (r,dst) segment.
// ---------------------------------------------------------------------------
__global__ __launch_bounds__(256) void count_all(
    const int* __restrict__ ei, const int* __restrict__ et,
    int* __restrict__ cnt, int* __restrict__ erank)
{
  int e = blockIdx.x * 256 + threadIdx.x;
  int dst = ei[EE + e], r = et[e];
  erank[e] = atomicAdd(&cnt[r * NN + dst], 1);
}

// ---------------------------------------------------------------------------
// 3-phase exclusive scan over cnt[K8] -> rowptr[K8+1].
// ---------------------------------------------------------------------------
__global__ __launch_bounds__(256) void scan_a(
    const int4* __restrict__ c4, int n4, int* __restrict__ bsum)
{
  int t = threadIdx.x;
  int s = 0;
#pragma unroll
  for (int i = 0; i < 4; ++i) {
    int idx = blockIdx.x * 1024 + i * 256 + t;
    if (idx < n4) { int4 v = c4[idx]; s += v.x + v.y + v.z + v.w; }
  }
  __shared__ int wsum[4];
  for (int d = 32; d; d >>= 1) s += __shfl_xor(s, d, 64);
  if ((t & 63) == 0) wsum[t >> 6] = s;
  __syncthreads();
  if (t == 0) bsum[blockIdx.x] = wsum[0] + wsum[1] + wsum[2] + wsum[3];
}

__global__ void scan_b(const int* __restrict__ bsum, int nsb,
                       int* __restrict__ bbase)
{
  int lane = threadIdx.x;                         // 64 threads
  int v[4]; int s = 0;
#pragma unroll
  for (int i = 0; i < 4; ++i) {
    int idx = lane * 4 + i;
    v[i] = (idx < nsb) ? bsum[idx] : 0; s += v[i];
  }
  int inc = s;
  for (int d = 1; d < 64; d <<= 1) {
    int o = __shfl_up(inc, d, 64);
    if (lane >= d) inc += o;
  }
  int running = inc - s;
#pragma unroll
  for (int i = 0; i < 4; ++i) {
    int idx = lane * 4 + i;
    if (idx < nsb) { bbase[idx] = running; running += v[i]; }
  }
}

__global__ __launch_bounds__(256) void scan_c(
    const int* __restrict__ cnt, const int* __restrict__ bbase, int n,
    int* __restrict__ out0)
{
  int t = threadIdx.x;
  int base = blockIdx.x * 4096 + t * 16;
  int v[16]; int s = 0;
#pragma unroll
  for (int i = 0; i < 16; ++i) {
    int idx = base + i;
    v[i] = (idx < n) ? cnt[idx] : 0;
    s += v[i];
  }
  int lane = t & 63, wid = t >> 6;
  int inc = s;
  for (int d = 1; d < 64; d <<= 1) {
    int o = __shfl_up(inc, d, 64);
    if (lane >= d) inc += o;
  }
  __shared__ int wsum[4];
  if (lane == 63) wsum[wid] = inc;
  __syncthreads();
  int wb = 0;
  for (int w = 0; w < wid; ++w) wb += wsum[w];
  int running = bbase[blockIdx.x] + wb + (inc - s);
#pragma unroll
  for (int i = 0; i < 16; ++i) {
    int idx = base + i;
    if (idx < n) { out0[idx] = running; running += v[i]; }
  }
  if (blockIdx.x == 0 && t == 0) out0[n] = EE;
}

// ---------------------------------------------------------------------------
// Place edges into (r,dst)-major CSR, no atomics. rec packs src (bits 0-19)
// and dst-in-64-block (bits 20-25): consumer block v0 is 64-aligned.
// ---------------------------------------------------------------------------
__global__ __launch_bounds__(256) void place(
    const int* __restrict__ ei, const int* __restrict__ et,
    const int* __restrict__ rowptr, const int* __restrict__ erank,
    int* __restrict__ recs)
{
  int e = blockIdx.x * 256 + threadIdx.x;
  int src = ei[e], dst = ei[EE + e], r = et[e];
  recs[rowptr[r * NN + dst] + erank[e]] = src | ((dst & 63) << 20);
}

// ---------------------------------------------------------------------------
// Fused aggregate-then-GEMM. Block owns 64 dst rows; wave w owns dsts
// [16w,16w+16) -> its edges per relation are a contiguous, dst-sorted span.
// Batch of 8 edges (8 lanes each, lane li owns cols li*4+32k): runs of equal
// dst combined in-register via segmented suffix-sum (shfl_down 8/16/32,
// skipped when batch has no duplicate dst); run-head group does a plain
// (non-atomic) LDS RMW into wave-private, col-swizzled accumulator rows.
// Convert phase scales by 1/cnt -> rotated bf16 A-tile; one MFMA round per
// relation (+root) accumulates in registers; epilogue = bias+ReLU+store.
// ---------------------------------------------------------------------------
__global__ __launch_bounds__(256, 3) void gemm_agg(
    const unsigned int* __restrict__ Xb,     // [NN][64] packed bf16 rows
    const unsigned short* __restrict__ Wt,   // [9][128][128] bf16 [r][n][k]
    const int* __restrict__ rowptr,          // [K8+1]
    const int* __restrict__ recs,            // [EE] packed (src, d6)
    const float* __restrict__ bias,          // [128]
    void* __restrict__ outp, int out_bf16)
{
  const int v0 = blockIdx.x * 64;
  __shared__ __align__(16) unsigned short As[64 * 128];  // 16 KB
  __shared__ __align__(16) float Accum[64 * 132];        // 33.8 KB
  __shared__ int Rp[8 * 65 + 8];

  const int tid = threadIdx.x;
  const int wave = tid >> 6, lane = tid & 63;
  const int quad = lane >> 4, mr = lane & 15;
  const int g = lane >> 3;         // edge-group within wave (0..7)
  const int li = lane & 7;         // lane-in-edge: owns cols li*4+32k
  const uint4v* Xb4 = (const uint4v*)Xb;
  unsigned int* Asu = (unsigned int*)As;

  // Rp[r*65 + j] = rowptr[r*NN + min(v0+j, NN)]  (clamped tail)
  for (int id = tid; id < 520; id += 256) {
    int r = id / 65, j = id - r * 65;
    Rp[id] = rowptr[r * NN + min(v0 + j, NN)];
  }
  for (int i = tid; i < 64 * 132; i += 256) Accum[i] = 0.f;

  floatx4 acc[4][2];
#pragma unroll
  for (int mi = 0; mi < 4; ++mi) {
    acc[mi][0] = (floatx4){0.f, 0.f, 0.f, 0.f};
    acc[mi][1] = (floatx4){0.f, 0.f, 0.f, 0.f};
  }
  __syncthreads();

  // ---- edge-parallel segment accumulate of relation rn (wave-private) ----
  auto ACCUM_REL = [&](int rn) {
    const int B = Rp[rn * 65 + wave * 16];
    const int E = Rp[rn * 65 + wave * 16 + 16];
    for (int eb = B; eb < E; eb += 8) {
      int e = eb + g;
      bool val = e < E;
      int rec = val ? recs[e] : 0;
      int d6  = val ? (rec >> 20) : -1;
      int src = rec & 0xFFFFF;
      float f[16];
#pragma unroll
      for (int j = 0; j < 16; ++j) f[j] = 0.f;
      if (val) {
#pragma unroll
        for (int k = 0; k < 4; ++k) {
          uint2 u = *(const uint2*)(Xb + (size_t)src * 64 + (li * 2 + 16 * k));
          f[4 * k + 0] = bflo(u.x); f[4 * k + 1] = bfhi(u.x);
          f[4 * k + 2] = bflo(u.y); f[4 * k + 3] = bfhi(u.y);
        }
      }
      int dprev = __shfl_up(d6, 8, 64);
      bool dup = val && (g > 0) && (dprev == d6);
      if (__any(dup)) {
        // segmented suffix-sum over groups (runs are contiguous)
#pragma unroll
        for (int st = 0; st < 3; ++st) {
          int delta = 8 << st;
          int dn = __shfl_down(d6, delta, 64);
          bool ok = val && ((lane + delta) < 64) && (dn == d6);
#pragma unroll
          for (int j = 0; j < 16; ++j) {
            float fj = __shfl_down(f[j], delta, 64);
            if (ok) f[j] += fj;
          }
        }
      }
      bool head = val && ((g == 0) || (dprev != d6));
      if (head) {
        float* acr = &Accum[d6 * 132];
#pragma unroll
        for (int k = 0; k < 4; ++k) {
          float* a4 = &acr[32 * k + ((li * 4) ^ (8 * k))];  // col-swizzle
          float4 cur = *(float4*)a4;
          cur.x += f[4 * k + 0]; cur.y += f[4 * k + 1];
          cur.z += f[4 * k + 2]; cur.w += f[4 * k + 3];
          *(float4*)a4 = cur;
        }
      }
    }
  };

  // ---- Accum -> As (scaled bf16, rotated), zero Accum ----
  auto CONVERT_REL = [&](int rn) {
    int d = tid >> 2, q = tid & 3;
    int cnt = Rp[rn * 65 + d + 1] - Rp[rn * 65 + d];
    float sc = 1.0f / (float)max(cnt, 1);
    int rot = (d & 15) * 4;
    float* ac = &Accum[d * 132 + q * 32];
    uint4v o[4];
#pragma unroll
    for (int c = 0; c < 4; ++c) {
      int sw = (8 * c) ^ (8 * q);              // inverse col-swizzle (k=q)
      float4 f0 = *(float4*)&ac[sw];
      float4 f1 = *(float4*)&ac[sw + 4];
      o[c][0] = pk2bf(f0.x * sc, f0.y * sc);
      o[c][1] = pk2bf(f0.z * sc, f0.w * sc);
      o[c][2] = pk2bf(f1.x * sc, f1.y * sc);
      o[c][3] = pk2bf(f1.z * sc, f1.w * sc);
      *(float4*)&ac[sw] = make_float4(0.f, 0.f, 0.f, 0.f);
      *(float4*)&ac[sw + 4] = make_float4(0.f, 0.f, 0.f, 0.f);
    }
#pragma unroll
    for (int c = 0; c < 4; ++c)
      *(uint4v*)&Asu[d * 64 + ((q * 16 + c * 4 + rot) & 63)] = o[c];
  };

  // ---- root rows staged through Accum (As is busy during MFMA) ----
  auto STAGE_ROOT = [&]() {
    int row = tid >> 2, q4 = tid & 3;
    int v = v0 + row;
    int src = (v < NN) ? v : 0;
    const uint4v* xs = Xb4 + (size_t)src * 16 + q4 * 4;
    unsigned* au = (unsigned*)Accum;
#pragma unroll
    for (int c = 0; c < 4; ++c) {
      uint4v vv = xs[c];
      *(uint4v*)&au[row * 132 + q4 * 16 + c * 4] = vv;
    }
  };
  auto CONVERT_ROOT = [&]() {
    int d = tid >> 2, q = tid & 3;
    int rot = (d & 15) * 4;
    unsigned* au = (unsigned*)Accum;
#pragma unroll
    for (int c = 0; c < 4; ++c) {
      uint4v vv = *(uint4v*)&au[d * 132 + q * 16 + c * 4];
      *(uint4v*)&Asu[d * 64 + ((q * 16 + c * 4 + rot) & 63)] = vv;
    }
  };

  // prologue: build relation-0 A-tile
  ACCUM_REL(0);
  __syncthreads();
  CONVERT_REL(0);
  __syncthreads();

#pragma unroll 1
  for (int r = 0; r < 9; ++r) {
    const unsigned short* wr =
        Wt + (size_t)r * 16384 + (size_t)(wave * 32 + mr) * 128 + quad * 8;
    short8 b0[4], b1[4];
#pragma unroll
    for (int ks = 0; ks < 4; ++ks) {
      b0[ks] = *(const short8*)(wr + ks * 32);
      b1[ks] = *(const short8*)(wr + 16 * 128 + ks * 32);
    }
#pragma unroll
    for (int ks = 0; ks < 4; ++ks) {
      short8 a[4];
#pragma unroll
      for (int mi = 0; mi < 4; ++mi)
        a[mi] = *(const short8*)&As[(mi * 16 + mr) * 128 +
                                    ((ks * 32 + quad * 8 + mr * 8) & 127)];
#pragma unroll
      for (int mi = 0; mi < 4; ++mi) {
        acc[mi][0] = __builtin_amdgcn_mfma_f32_16x16x32_bf16(a[mi], b0[ks], acc[mi][0], 0, 0, 0);
        acc[mi][1] = __builtin_amdgcn_mfma_f32_16x16x32_bf16(a[mi], b1[ks], acc[mi][1], 0, 0, 0);
      }
    }
    if (r < 7) ACCUM_REL(r + 1);
    else if (r == 7) STAGE_ROOT();
    __syncthreads();
    if (r < 7) CONVERT_REL(r + 1);
    else if (r == 7) CONVERT_ROOT();
    __syncthreads();
  }

  // ---- epilogue: bias + ReLU, direct store ----
  float bia0 = bias[wave * 32 + mr], bia1 = bias[wave * 32 + 16 + mr];
#pragma unroll
  for (int mi = 0; mi < 4; ++mi)
#pragma unroll
    for (int rg = 0; rg < 4; ++rg) {
      int row = mi * 16 + quad * 4 + rg;
      int v = v0 + row;
      if (v < NN) {
        float c0 = fmaxf(acc[mi][0][rg] + bia0, 0.f);
        float c1 = fmaxf(acc[mi][1][rg] + bia1, 0.f);
        if (out_bf16) {
          ((unsigned int*)outp)[(size_t)v * 64 + wave * 16 + mr] = pk2bf(c0, c1);
        } else {
          float* o = (float*)outp;
          o[(size_t)v * 128 + wave * 32 + mr] = c0;
          o[(size_t)v * 128 + wave * 32 + 16 + mr] = c1;
        }
      }
    }
}

// ---------------------------------------------------------------------------
extern "C" void kernel_launch(void* const* d_in, const int* in_sizes, int n_in,
                              void* d_out, int out_size, void* d_ws, size_t ws_size,
                              hipStream_t stream) {
  const float* x       = (const float*)d_in[0];
  const int*   ei      = (const int*)d_in[1];
  const int*   et      = (const int*)d_in[2];
  const float* rel_w1  = (const float*)d_in[3];
  const float* root_w1 = (const float*)d_in[4];
  const float* b1      = (const float*)d_in[5];
  const float* rel_w2  = (const float*)d_in[6];
  const float* root_w2 = (const float*)d_in[7];
  const float* b2      = (const float*)d_in[8];

  char* ws = (char*)d_ws;
  size_t off = 0;
  auto alloc = [&](size_t bytes) { char* p = ws + off; off = (off + bytes + 255) & ~(size_t)255; return p; };
  unsigned int*   Xb    = (unsigned int*)alloc((size_t)NN * 64 * 4);         // 25.6 MB
  unsigned int*   h1    = (unsigned int*)alloc((size_t)NN * 64 * 4);         // 25.6 MB (permuted pack)
  unsigned short* Wt    = (unsigned short*)alloc((size_t)2 * 9 * DD * DD * 2);
  int*            cnt   = (int*)alloc((size_t)K8 * 4);                       // 3.2 MB (zeroed)
  int*            rowptr= (int*)alloc((size_t)(K8 + 1) * 4);                 // 3.2 MB
  int*            erank = (int*)alloc((size_t)EE * 4);                       // 2.56 MB
  int*            recs  = (int*)alloc((size_t)EE * 4);                       // 2.56 MB
  int*            bsum  = (int*)alloc((size_t)NSB2 * 4);
  int*            bbase = (int*)alloc((size_t)NSB2 * 4);

  hipMemsetAsync(cnt, 0, (size_t)K8 * 4, stream);

  xb_prep<<<(NN * 16) / 256, 256, 0, stream>>>(x, Xb);
  w_prep_all<<<(2 * 9 * DD * DD) / 256, 256, 0, stream>>>(rel_w1, root_w1, rel_w2, root_w2, Wt);
  count_all<<<EE / 256, 256, 0, stream>>>(ei, et, cnt, erank);

  scan_a<<<NSB2, 256, 0, stream>>>((const int4*)cnt, K8 / 4, bsum);
  scan_b<<<1, 64, 0, stream>>>(bsum, NSB2, bbase);
  scan_c<<<NSB2, 256, 0, stream>>>(cnt, bbase, K8, rowptr);

  place<<<EE / 256, 256, 0, stream>>>(ei, et, rowptr, erank, recs);

  gemm_agg<<<NB, 256, 0, stream>>>(Xb, Wt, rowptr, recs, b1, h1, 1);
  gemm_agg<<<NB, 256, 0, stream>>>(h1, Wt + (size_t)9 * DD * DD, rowptr, recs, b2, d_out, 0);
}

// Round 5
// 439.792 us; speedup vs baseline: 2.8922x; 1.1475x over previous
//
#include <hip/hip_runtime.h>
#include <hip/hip_bf16.h>

#define NN 100000
#define EE 640000
#define DD 128
#define RR 8
#define K8 (NN * RR)      // 800000 (rel,dst) pair keys, key = r*NN + dst
#define NSB2 196          // ceil(K8/4096)
#define NB 1563           // ceil(NN/64) gemm blocks
#define AGB 20000         // EE*8/256 agg blocks (worst-case rows = EE)

typedef __attribute__((ext_vector_type(8))) short short8;
typedef __attribute__((ext_vector_type(4))) float floatx4;
typedef __attribute__((ext_vector_type(4))) unsigned int uint4v;

__device__ __forceinline__ unsigned short f2bf(float f) {
  unsigned int u = __float_as_uint(f);
  u += 0x7FFFu + ((u >> 16) & 1u);   // RNE
  return (unsigned short)(u >> 16);
}
__device__ __forceinline__ unsigned int pk2bf(float a, float b) {
  __hip_bfloat162 h = __float22bfloat162_rn(make_float2(a, b));
  unsigned int u;
  __builtin_memcpy(&u, &h, 4);
  return u;                          // low16 = a, high16 = b
}
__device__ __forceinline__ float bflo(unsigned int u) { return __uint_as_float(u << 16); }
__device__ __forceinline__ float bfhi(unsigned int u) { return __uint_as_float(u & 0xFFFF0000u); }

// ---------------------------------------------------------------------------
// x (fp32 [NN][128]) -> Xb (bf16 std rows as uints: uint j = cols 2j|2j+1<<16)
// ---------------------------------------------------------------------------
__global__ __launch_bounds__(256) void xb_prep(
    const float* __restrict__ x, unsigned int* __restrict__ xb)
{
  int g = blockIdx.x * 256 + threadIdx.x;
  int v = g >> 4, seg = g & 15;
  const float4* s4 = (const float4*)(x + (size_t)v * 128 + seg * 8);
  float4 a = s4[0], b = s4[1];
  uint4v o;
  o[0] = pk2bf(a.x, a.y); o[1] = pk2bf(a.z, a.w);
  o[2] = pk2bf(b.x, b.y); o[3] = pk2bf(b.z, b.w);
  *(uint4v*)(xb + (size_t)v * 64 + seg * 4) = o;
}

// ---------------------------------------------------------------------------
// Weights: wt[set][r][n][k] = bf16(W[kk][n]); r=8 is root. Set 1 permutes k
// to match layer-1's packed epilogue layout.
// ---------------------------------------------------------------------------
__global__ __launch_bounds__(256) void w_prep_all(
    const float* __restrict__ rel1, const float* __restrict__ root1,
    const float* __restrict__ rel2, const float* __restrict__ root2,
    unsigned short* __restrict__ wt)
{
  int id = blockIdx.x * 256 + threadIdx.x;       // [0, 2*9*16384)
  int set = id >= 147456;
  int rem = id - set * 147456;
  int r = rem >> 14, n = (rem >> 7) & 127, k = rem & 127;
  int kk = k;
  if (set) {
    int u = k >> 1, w2 = u >> 4, m2 = u & 15;
    kk = w2 * 32 + m2 + ((k & 1) << 4);
  }
  const float* rel = set ? rel2 : rel1;
  const float* root = set ? root2 : root1;
  float v = (r < RR) ? rel[((size_t)r * DD + kk) * DD + n] : root[(size_t)kk * DD + n];
  wt[id] = f2bf(v);
}

// ---------------------------------------------------------------------------
// One atomic per edge; return value = rank in (r,dst) segment.
// ---------------------------------------------------------------------------
__global__ __launch_bounds__(256) void count_all(
    const int* __restrict__ ei, const int* __restrict__ et,
    int* __restrict__ cnt, int* __restrict__ erank)
{
  int e = blockIdx.x * 256 + threadIdx.x;
  int dst = ei[EE + e], r = et[e];
  erank[e] = atomicAdd(&cnt[r * NN + dst], 1);
}

// ---------------------------------------------------------------------------
// 3-phase exclusive scans over cnt[K8]. mode 0: sum values -> rowptr.
// mode 1: count nonzero -> rank compaction (pidx or -1).
// ---------------------------------------------------------------------------
__global__ __launch_bounds__(256) void scan_a(
    const int4* __restrict__ c4, int n4, int mode, int* __restrict__ bsum)
{
  int t = threadIdx.x;
  int s = 0;
#pragma unroll
  for (int i = 0; i < 4; ++i) {
    int idx = blockIdx.x * 1024 + i * 256 + t;
    if (idx < n4) {
      int4 v = c4[idx];
      if (mode) s += (v.x > 0) + (v.y > 0) + (v.z > 0) + (v.w > 0);
      else      s += v.x + v.y + v.z + v.w;
    }
  }
  __shared__ int wsum[4];
  for (int d = 32; d; d >>= 1) s += __shfl_xor(s, d, 64);
  if ((t & 63) == 0) wsum[t >> 6] = s;
  __syncthreads();
  if (t == 0) bsum[blockIdx.x] = wsum[0] + wsum[1] + wsum[2] + wsum[3];
}

__global__ void scan_b(const int* __restrict__ bsum, int nsb,
                       int* __restrict__ bbase, int* __restrict__ tot)
{
  int lane = threadIdx.x;                         // 64 threads
  int v[4]; int s = 0;
#pragma unroll
  for (int i = 0; i < 4; ++i) {
    int idx = lane * 4 + i;
    v[i] = (idx < nsb) ? bsum[idx] : 0; s += v[i];
  }
  int inc = s;
  for (int d = 1; d < 64; d <<= 1) {
    int o = __shfl_up(inc, d, 64);
    if (lane >= d) inc += o;
  }
  int running = inc - s;
#pragma unroll
  for (int i = 0; i < 4; ++i) {
    int idx = lane * 4 + i;
    if (idx < nsb) { bbase[idx] = running; running += v[i]; }
  }
  if (lane == 63 && tot != nullptr) tot[0] = inc;
}

__global__ __launch_bounds__(256) void scan_c(
    const int* __restrict__ cnt, const int* __restrict__ bbase, int n, int mode,
    int* __restrict__ out0)
{
  int t = threadIdx.x;
  int base = blockIdx.x * 4096 + t * 16;
  int v[16]; int s = 0;
#pragma unroll
  for (int i = 0; i < 16; ++i) {
    int idx = base + i;
    v[i] = (idx < n) ? cnt[idx] : 0;
    s += mode ? (v[i] > 0) : v[i];
  }
  int lane = t & 63, wid = t >> 6;
  int inc = s;
  for (int d = 1; d < 64; d <<= 1) {
    int o = __shfl_up(inc, d, 64);
    if (lane >= d) inc += o;
  }
  __shared__ int wsum[4];
  if (lane == 63) wsum[wid] = inc;
  __syncthreads();
  int wb = 0;
  for (int w = 0; w < wid; ++w) wb += wsum[w];
  int running = bbase[blockIdx.x] + wb + (inc - s);
#pragma unroll
  for (int i = 0; i < 16; ++i) {
    int idx = base + i;
    if (idx < n) {
      if (mode) { out0[idx] = (v[i] > 0) ? running : -1; running += (v[i] > 0); }
      else      { out0[idx] = running; running += v[i]; }
    }
  }
  if (!mode && blockIdx.x == 0 && t == 0) out0[n] = EE;
}

// ---------------------------------------------------------------------------
// erowptr[pidx[k]] = rowptr[k] for present keys; erowptr[nrows] = EE.
// Rows beyond nrows stay 0 (memset) -> agg groups skip them (end<=beg).
// ---------------------------------------------------------------------------
__global__ __launch_bounds__(256) void erow_fill(
    const int* __restrict__ pidx, const int* __restrict__ rowptr,
    const int* __restrict__ tot, int* __restrict__ erowptr)
{
  int k = blockIdx.x * 256 + threadIdx.x;
  int p = pidx[k];
  if (p >= 0) erowptr[p] = rowptr[k];
  if (k == 0) erowptr[tot[0]] = EE;
}

// ---------------------------------------------------------------------------
// Place edge srcs into (r,dst)-major CSR, no atomics.
// ---------------------------------------------------------------------------
__global__ __launch_bounds__(256) void place(
    const int* __restrict__ ei, const int* __restrict__ et,
    const int* __restrict__ rowptr, const int* __restrict__ erank,
    int* __restrict__ recs)
{
  int e = blockIdx.x * 256 + threadIdx.x;
  int src = ei[e], dst = ei[EE + e], r = et[e];
  recs[rowptr[r * NN + dst] + erank[e]] = src;
}

// ---------------------------------------------------------------------------
// Segment means: one 8-lane group per compacted (r,dst) row. Lane li owns a
// 32 B slice. cnt==1 (65% of rows): raw bf16 copy. cnt>1: f32 accumulate,
// scale, repack. Reads hit the 25.6 MB L3-resident Xin; writes coalesced.
// ---------------------------------------------------------------------------
__global__ __launch_bounds__(256) void agg_kernel(
    const unsigned int* __restrict__ Xin,    // [NN][64] packed bf16 rows
    const int* __restrict__ erowptr,         // [<=EE+1] edge span per row
    const int* __restrict__ recs,            // [EE] src per slot
    unsigned int* __restrict__ Agg)          // [<=EE][64]
{
  int gid = blockIdx.x * 256 + threadIdx.x;
  int row = gid >> 3, li = gid & 7;
  int beg = erowptr[row], end = erowptr[row + 1];
  if (end <= beg) return;
  const uint4v* X4 = (const uint4v*)Xin;
  uint4v o0, o1;
  int cnt = end - beg;
  if (cnt == 1) {
    int src = recs[beg];
    const uint4v* xp = X4 + (size_t)src * 16 + li * 2;
    o0 = xp[0]; o1 = xp[1];
  } else {
    float f[16];
#pragma unroll
    for (int j = 0; j < 16; ++j) f[j] = 0.f;
    for (int e = beg; e < end; ++e) {
      int src = recs[e];
      const uint4v* xp = X4 + (size_t)src * 16 + li * 2;
      uint4v u0 = xp[0], u1 = xp[1];
      unsigned um[8];
      *(uint4v*)&um[0] = u0; *(uint4v*)&um[4] = u1;
#pragma unroll
      for (int m = 0; m < 8; ++m) {
        f[2 * m]     += bflo(um[m]);
        f[2 * m + 1] += bfhi(um[m]);
      }
    }
    float sc = 1.0f / (float)cnt;
#pragma unroll
    for (int m = 0; m < 4; ++m) o0[m] = pk2bf(f[2 * m] * sc, f[2 * m + 1] * sc);
#pragma unroll
    for (int m = 0; m < 4; ++m) o1[m] = pk2bf(f[8 + 2 * m] * sc, f[9 + 2 * m] * sc);
  }
  uint4v* op = (uint4v*)Agg + (size_t)row * 16 + li * 2;
  op[0] = o0; op[1] = o1;
}

// ---------------------------------------------------------------------------
// GEMM over aggregated rows. Block owns 64 dsts. Per relation r the present
// Agg rows are a CONTIGUOUS ascending run (pidx is a rank over (r,dst) keys)
// -> sequential coalesced stage; absent dsts zero-filled. 9 MFMA rounds
// (8 rel + root from Xin) accumulate in registers; bias+ReLU epilogue.
// ---------------------------------------------------------------------------
__global__ __launch_bounds__(256, 4) void gemm_final(
    const unsigned int* __restrict__ Xin,    // [NN][64] root input
    const unsigned int* __restrict__ Agg,    // [<=EE][64] aggregated rows
    const unsigned short* __restrict__ Wt,   // [9][128][128] bf16 [r][n][k]
    const int* __restrict__ pidx,            // [K8] rank or -1
    const float* __restrict__ bias,          // [128]
    void* __restrict__ outp, int out_bf16)
{
  const int v0 = blockIdx.x * 64;
  __shared__ __align__(16) unsigned short As[64 * 128];  // 16 KB
  __shared__ int Pr[8 * 64];                             // 2 KB

  const int tid = threadIdx.x;
  const int wave = tid >> 6, lane = tid & 63;
  const int quad = lane >> 4, mr = lane & 15;
  const int row = tid >> 2, q = tid & 3;
  const uint4v* Agg4 = (const uint4v*)Agg;
  const uint4v* Xin4 = (const uint4v*)Xin;

  for (int id = tid; id < 512; id += 256) {
    int r = id >> 6, d = id & 63;
    int v = v0 + d;
    Pr[id] = (v < NN) ? pidx[r * NN + v] : -1;
  }

  floatx4 acc[4][2];
#pragma unroll
  for (int mi = 0; mi < 4; ++mi) {
    acc[mi][0] = (floatx4){0.f, 0.f, 0.f, 0.f};
    acc[mi][1] = (floatx4){0.f, 0.f, 0.f, 0.f};
  }
  __syncthreads();

#pragma unroll 1
  for (int r = 0; r < 9; ++r) {
    // B fragments for W_r (L2-resident)
    const unsigned short* wr =
        Wt + (size_t)r * 16384 + (size_t)(wave * 32 + mr) * 128 + quad * 8;
    short8 b0[4], b1[4];
#pragma unroll
    for (int ks = 0; ks < 4; ++ks) {
      b0[ks] = *(const short8*)(wr + ks * 32);
      b1[ks] = *(const short8*)(wr + 16 * 128 + ks * 32);
    }
    // ---- stage A-tile (rotated) ----
    const uint4v* sp = nullptr;
    if (r < 8) {
      int p = Pr[r * 64 + row];
      if (p >= 0) sp = Agg4 + (size_t)p * 16 + q * 4;
    } else {
      int v = v0 + row;
      if (v < NN) sp = Xin4 + (size_t)v * 16 + q * 4;
    }
    uint4v vals[4];
#pragma unroll
    for (int c = 0; c < 4; ++c)
      vals[c] = sp ? sp[c] : (uint4v){0u, 0u, 0u, 0u};
#pragma unroll
    for (int c = 0; c < 4; ++c) {
      int pos = (q * 32 + c * 8 + (row & 15) * 8) & 127;
      *(uint4v*)&As[row * 128 + pos] = vals[c];
    }
    __syncthreads();
    // ---- MFMA round ----
#pragma unroll
    for (int ks = 0; ks < 4; ++ks) {
      short8 a[4];
#pragma unroll
      for (int mi = 0; mi < 4; ++mi)
        a[mi] = *(const short8*)&As[(mi * 16 + mr) * 128 +
                                    ((ks * 32 + quad * 8 + mr * 8) & 127)];
#pragma unroll
      for (int mi = 0; mi < 4; ++mi) {
        acc[mi][0] = __builtin_amdgcn_mfma_f32_16x16x32_bf16(a[mi], b0[ks], acc[mi][0], 0, 0, 0);
        acc[mi][1] = __builtin_amdgcn_mfma_f32_16x16x32_bf16(a[mi], b1[ks], acc[mi][1], 0, 0, 0);
      }
    }
    __syncthreads();
  }

  // ---- epilogue: bias + ReLU, direct store ----
  float bia0 = bias[wave * 32 + mr], bia1 = bias[wave * 32 + 16 + mr];
#pragma unroll
  for (int mi = 0; mi < 4; ++mi)
#pragma unroll
    for (int rg = 0; rg < 4; ++rg) {
      int rw = mi * 16 + quad * 4 + rg;
      int v = v0 + rw;
      if (v < NN) {
        float c0 = fmaxf(acc[mi][0][rg] + bia0, 0.f);
        float c1 = fmaxf(acc[mi][1][rg] + bia1, 0.f);
        if (out_bf16) {
          ((unsigned int*)outp)[(size_t)v * 64 + wave * 16 + mr] = pk2bf(c0, c1);
        } else {
          float* o = (float*)outp;
          o[(size_t)v * 128 + wave * 32 + mr] = c0;
          o[(size_t)v * 128 + wave * 32 + 16 + mr] = c1;
        }
      }
    }
}

// ---------------------------------------------------------------------------
extern "C" void kernel_launch(void* const* d_in, const int* in_sizes, int n_in,
                              void* d_out, int out_size, void* d_ws, size_t ws_size,
                              hipStream_t stream) {
  const float* x       = (const float*)d_in[0];
  const int*   ei      = (const int*)d_in[1];
  const int*   et      = (const int*)d_in[2];
  const float* rel_w1  = (const float*)d_in[3];
  const float* root_w1 = (const float*)d_in[4];
  const float* b1      = (const float*)d_in[5];
  const float* rel_w2  = (const float*)d_in[6];
  const float* root_w2 = (const float*)d_in[7];
  const float* b2      = (const float*)d_in[8];

  char* ws = (char*)d_ws;
  size_t off = 0;
  auto alloc = [&](size_t bytes) { char* p = ws + off; off = (off + bytes + 255) & ~(size_t)255; return p; };
  unsigned int*   Xb    = (unsigned int*)alloc((size_t)NN * 64 * 4);         // 25.6 MB
  unsigned int*   h1    = (unsigned int*)alloc((size_t)NN * 64 * 4);         // 25.6 MB (permuted pack)
  unsigned int*   Agg   = (unsigned int*)alloc((size_t)EE * 64 * 4);         // 163.8 MB (worst case)
  unsigned short* Wt    = (unsigned short*)alloc((size_t)2 * 9 * DD * DD * 2);
  // ---- zero span: cnt + erowptr ----
  int*            cnt   = (int*)alloc((size_t)K8 * 4);                       // 3.2 MB
  int*            erowptr = (int*)alloc((size_t)(EE + 2) * 4);               // 2.56 MB
  char*           zend  = ws + off;
  // ---- rest ----
  int*            rowptr= (int*)alloc((size_t)(K8 + 1) * 4);                 // 3.2 MB
  int*            pidx  = (int*)alloc((size_t)K8 * 4);                       // 3.2 MB
  int*            erank = (int*)alloc((size_t)EE * 4);                       // 2.56 MB
  int*            recs  = (int*)alloc((size_t)EE * 4);                       // 2.56 MB
  int*            bsumA = (int*)alloc((size_t)NSB2 * 4);
  int*            bbaseA= (int*)alloc((size_t)NSB2 * 4);
  int*            bsumB = (int*)alloc((size_t)NSB2 * 4);
  int*            bbaseB= (int*)alloc((size_t)NSB2 * 4);
  int*            Ptot  = (int*)alloc(64);

  hipMemsetAsync(cnt, 0, (size_t)(zend - (char*)cnt), stream);

  xb_prep<<<(NN * 16) / 256, 256, 0, stream>>>(x, Xb);
  w_prep_all<<<(2 * 9 * DD * DD) / 256, 256, 0, stream>>>(rel_w1, root_w1, rel_w2, root_w2, Wt);
  count_all<<<EE / 256, 256, 0, stream>>>(ei, et, cnt, erank);

  // pass 1: rowptr (edge offsets per key)
  scan_a<<<NSB2, 256, 0, stream>>>((const int4*)cnt, K8 / 4, 0, bsumA);
  scan_b<<<1, 64, 0, stream>>>(bsumA, NSB2, bbaseA, nullptr);
  scan_c<<<NSB2, 256, 0, stream>>>(cnt, bbaseA, K8, 0, rowptr);

  // pass 2: rank compaction (pidx) + total rows
  scan_a<<<NSB2, 256, 0, stream>>>((const int4*)cnt, K8 / 4, 1, bsumB);
  scan_b<<<1, 64, 0, stream>>>(bsumB, NSB2, bbaseB, Ptot);
  scan_c<<<NSB2, 256, 0, stream>>>(cnt, bbaseB, K8, 1, pidx);

  erow_fill<<<K8 / 256, 256, 0, stream>>>(pidx, rowptr, Ptot, erowptr);
  place<<<EE / 256, 256, 0, stream>>>(ei, et, rowptr, erank, recs);

  agg_kernel<<<AGB, 256, 0, stream>>>(Xb, erowptr, recs, Agg);
  gemm_final<<<NB, 256, 0, stream>>>(Xb, Agg, Wt, pidx, b1, h1, 1);
  agg_kernel<<<AGB, 256, 0, stream>>>(h1, erowptr, recs, Agg);
  gemm_final<<<NB, 256, 0, stream>>>(h1, Agg, Wt + (size_t)9 * DD * DD, pidx, b2, d_out, 0);
}

// Round 6
// 437.287 us; speedup vs baseline: 2.9087x; 1.0057x over previous
//
#include <hip/hip_runtime.h>
#include <hip/hip_bf16.h>

#define NN 100000
#define EE 640000
#define DD 128
#define RR 8
#define K8 (NN * RR)      // 800000 (rel,dst) pair keys, key = r*NN + dst
#define NSB2 196          // ceil(K8/4096)
#define NB 1563           // ceil(NN/64) gemm blocks
#define AGB 20000         // EE*8/256 agg blocks (worst-case rows = EE)

typedef __attribute__((ext_vector_type(8))) short short8;
typedef __attribute__((ext_vector_type(4))) float floatx4;
typedef __attribute__((ext_vector_type(4))) unsigned int uint4v;

__device__ __forceinline__ unsigned short f2bf(float f) {
  unsigned int u = __float_as_uint(f);
  u += 0x7FFFu + ((u >> 16) & 1u);   // RNE
  return (unsigned short)(u >> 16);
}
__device__ __forceinline__ unsigned int pk2bf(float a, float b) {
  __hip_bfloat162 h = __float22bfloat162_rn(make_float2(a, b));
  unsigned int u;
  __builtin_memcpy(&u, &h, 4);
  return u;                          // low16 = a, high16 = b
}
__device__ __forceinline__ float bflo(unsigned int u) { return __uint_as_float(u << 16); }
__device__ __forceinline__ float bfhi(unsigned int u) { return __uint_as_float(u & 0xFFFF0000u); }

// ---------------------------------------------------------------------------
// x (fp32 [NN][128]) -> Xb (bf16 std rows as uints: uint j = cols 2j|2j+1<<16)
// ---------------------------------------------------------------------------
__global__ __launch_bounds__(256) void xb_prep(
    const float* __restrict__ x, unsigned int* __restrict__ xb)
{
  int g = blockIdx.x * 256 + threadIdx.x;
  int v = g >> 4, seg = g & 15;
  const float4* s4 = (const float4*)(x + (size_t)v * 128 + seg * 8);
  float4 a = s4[0], b = s4[1];
  uint4v o;
  o[0] = pk2bf(a.x, a.y); o[1] = pk2bf(a.z, a.w);
  o[2] = pk2bf(b.x, b.y); o[3] = pk2bf(b.z, b.w);
  *(uint4v*)(xb + (size_t)v * 64 + seg * 4) = o;
}

// ---------------------------------------------------------------------------
// Weights: wt[set][r][n][k] = bf16(W[kk][n]); r=8 is root. Set 1 permutes k
// to match layer-1's packed epilogue layout.
// ---------------------------------------------------------------------------
__global__ __launch_bounds__(256) void w_prep_all(
    const float* __restrict__ rel1, const float* __restrict__ root1,
    const float* __restrict__ rel2, const float* __restrict__ root2,
    unsigned short* __restrict__ wt)
{
  int id = blockIdx.x * 256 + threadIdx.x;       // [0, 2*9*16384)
  int set = id >= 147456;
  int rem = id - set * 147456;
  int r = rem >> 14, n = (rem >> 7) & 127, k = rem & 127;
  int kk = k;
  if (set) {
    int u = k >> 1, w2 = u >> 4, m2 = u & 15;
    kk = w2 * 32 + m2 + ((k & 1) << 4);
  }
  const float* rel = set ? rel2 : rel1;
  const float* root = set ? root2 : root1;
  float v = (r < RR) ? rel[((size_t)r * DD + kk) * DD + n] : root[(size_t)kk * DD + n];
  wt[id] = f2bf(v);
}

// ---------------------------------------------------------------------------
// One atomic per edge; return value = rank in (r,dst) segment.
// ---------------------------------------------------------------------------
__global__ __launch_bounds__(256) void count_all(
    const int* __restrict__ ei, const int* __restrict__ et,
    int* __restrict__ cnt, int* __restrict__ erank)
{
  int e = blockIdx.x * 256 + threadIdx.x;
  int dst = ei[EE + e], r = et[e];
  erank[e] = atomicAdd(&cnt[r * NN + dst], 1);
}

// ---------------------------------------------------------------------------
// 3-phase exclusive scans over cnt[K8]. mode 0: sum values -> rowptr.
// mode 1: count nonzero -> rank compaction (pidx or -1).
// ---------------------------------------------------------------------------
__global__ __launch_bounds__(256) void scan_a(
    const int4* __restrict__ c4, int n4, int mode, int* __restrict__ bsum)
{
  int t = threadIdx.x;
  int s = 0;
#pragma unroll
  for (int i = 0; i < 4; ++i) {
    int idx = blockIdx.x * 1024 + i * 256 + t;
    if (idx < n4) {
      int4 v = c4[idx];
      if (mode) s += (v.x > 0) + (v.y > 0) + (v.z > 0) + (v.w > 0);
      else      s += v.x + v.y + v.z + v.w;
    }
  }
  __shared__ int wsum[4];
  for (int d = 32; d; d >>= 1) s += __shfl_xor(s, d, 64);
  if ((t & 63) == 0) wsum[t >> 6] = s;
  __syncthreads();
  if (t == 0) bsum[blockIdx.x] = wsum[0] + wsum[1] + wsum[2] + wsum[3];
}

__global__ void scan_b(const int* __restrict__ bsum, int nsb,
                       int* __restrict__ bbase, int* __restrict__ tot)
{
  int lane = threadIdx.x;                         // 64 threads
  int v[4]; int s = 0;
#pragma unroll
  for (int i = 0; i < 4; ++i) {
    int idx = lane * 4 + i;
    v[i] = (idx < nsb) ? bsum[idx] : 0; s += v[i];
  }
  int inc = s;
  for (int d = 1; d < 64; d <<= 1) {
    int o = __shfl_up(inc, d, 64);
    if (lane >= d) inc += o;
  }
  int running = inc - s;
#pragma unroll
  for (int i = 0; i < 4; ++i) {
    int idx = lane * 4 + i;
    if (idx < nsb) { bbase[idx] = running; running += v[i]; }
  }
  if (lane == 63 && tot != nullptr) tot[0] = inc;
}

__global__ __launch_bounds__(256) void scan_c(
    const int* __restrict__ cnt, const int* __restrict__ bbase, int n, int mode,
    int* __restrict__ out0)
{
  int t = threadIdx.x;
  int base = blockIdx.x * 4096 + t * 16;
  int v[16]; int s = 0;
#pragma unroll
  for (int i = 0; i < 16; ++i) {
    int idx = base + i;
    v[i] = (idx < n) ? cnt[idx] : 0;
    s += mode ? (v[i] > 0) : v[i];
  }
  int lane = t & 63, wid = t >> 6;
  int inc = s;
  for (int d = 1; d < 64; d <<= 1) {
    int o = __shfl_up(inc, d, 64);
    if (lane >= d) inc += o;
  }
  __shared__ int wsum[4];
  if (lane == 63) wsum[wid] = inc;
  __syncthreads();
  int wb = 0;
  for (int w = 0; w < wid; ++w) wb += wsum[w];
  int running = bbase[blockIdx.x] + wb + (inc - s);
#pragma unroll
  for (int i = 0; i < 16; ++i) {
    int idx = base + i;
    if (idx < n) {
      if (mode) { out0[idx] = (v[i] > 0) ? running : -1; running += (v[i] > 0); }
      else      { out0[idx] = running; running += v[i]; }
    }
  }
  if (!mode && blockIdx.x == 0 && t == 0) out0[n] = EE;
}

// ---------------------------------------------------------------------------
// erowptr[pidx[k]] = rowptr[k] for present keys; erowptr[nrows] = EE.
// Rows beyond nrows stay 0 (memset) -> agg groups skip them (end<=beg).
// ---------------------------------------------------------------------------
__global__ __launch_bounds__(256) void erow_fill(
    const int* __restrict__ pidx, const int* __restrict__ rowptr,
    const int* __restrict__ tot, int* __restrict__ erowptr)
{
  int k = blockIdx.x * 256 + threadIdx.x;
  int p = pidx[k];
  if (p >= 0) erowptr[p] = rowptr[k];
  if (k == 0) erowptr[tot[0]] = EE;
}

// ---------------------------------------------------------------------------
// Place edge srcs into (r,dst)-major CSR, no atomics.
// ---------------------------------------------------------------------------
__global__ __launch_bounds__(256) void place(
    const int* __restrict__ ei, const int* __restrict__ et,
    const int* __restrict__ rowptr, const int* __restrict__ erank,
    int* __restrict__ recs)
{
  int e = blockIdx.x * 256 + threadIdx.x;
  int src = ei[e], dst = ei[EE + e], r = et[e];
  recs[rowptr[r * NN + dst] + erank[e]] = src;
}

// ---------------------------------------------------------------------------
// Segment means: one 8-lane group per compacted (r,dst) row. Lane li owns a
// 32 B slice. cnt==1 (65% of rows): raw bf16 copy. cnt>1: f32 accumulate,
// scale, repack. Reads hit the 25.6 MB L3-resident Xin; writes coalesced.
// ---------------------------------------------------------------------------
__global__ __launch_bounds__(256) void agg_kernel(
    const unsigned int* __restrict__ Xin,    // [NN][64] packed bf16 rows
    const int* __restrict__ erowptr,         // [<=EE+1] edge span per row
    const int* __restrict__ recs,            // [EE] src per slot
    unsigned int* __restrict__ Agg)          // [<=EE][64]
{
  int gid = blockIdx.x * 256 + threadIdx.x;
  int row = gid >> 3, li = gid & 7;
  int beg = erowptr[row], end = erowptr[row + 1];
  if (end <= beg) return;
  const uint4v* X4 = (const uint4v*)Xin;
  uint4v o0, o1;
  int cnt = end - beg;
  if (cnt == 1) {
    int src = recs[beg];
    const uint4v* xp = X4 + (size_t)src * 16 + li * 2;
    o0 = xp[0]; o1 = xp[1];
  } else {
    float f[16];
#pragma unroll
    for (int j = 0; j < 16; ++j) f[j] = 0.f;
    for (int e = beg; e < end; ++e) {
      int src = recs[e];
      const uint4v* xp = X4 + (size_t)src * 16 + li * 2;
      uint4v u0 = xp[0], u1 = xp[1];
      unsigned um[8];
      *(uint4v*)&um[0] = u0; *(uint4v*)&um[4] = u1;
#pragma unroll
      for (int m = 0; m < 8; ++m) {
        f[2 * m]     += bflo(um[m]);
        f[2 * m + 1] += bfhi(um[m]);
      }
    }
    float sc = 1.0f / (float)cnt;
#pragma unroll
    for (int m = 0; m < 4; ++m) o0[m] = pk2bf(f[2 * m] * sc, f[2 * m + 1] * sc);
#pragma unroll
    for (int m = 0; m < 4; ++m) o1[m] = pk2bf(f[8 + 2 * m] * sc, f[9 + 2 * m] * sc);
  }
  uint4v* op = (uint4v*)Agg + (size_t)row * 16 + li * 2;
  op[0] = o0; op[1] = o1;
}

// ---------------------------------------------------------------------------
// GEMM over aggregated rows, software-pipelined. Block owns 64 dsts.
// Double-buffered LDS A-tiles staged by async global_load_lds with the
// rotation applied on the per-lane GLOBAL source address (dest chunk j of
// row d reads source chunk (j - (d&15)) & 15). One barrier per round: at
// round r, issue r+1's loads into the free buffer, prefetch B(r+1) to regs,
// MFMA round r, then __syncthreads() (vmcnt drain completes r+1's tile).
// Absent (r,dst) rows and tail rows read a 256 B zero page.
// ---------------------------------------------------------------------------
__global__ __launch_bounds__(256, 4) void gemm_final(
    const unsigned int* __restrict__ Xin,    // [NN][64] root input
    const unsigned int* __restrict__ Agg,    // [<=EE][64] aggregated rows
    const unsigned short* __restrict__ Wt,   // [9][128][128] bf16 [r][n][k]
    const int* __restrict__ pidx,            // [K8] rank or -1
    const unsigned int* __restrict__ Zrow,   // [64] zeros (256 B)
    const float* __restrict__ bias,          // [128]
    void* __restrict__ outp, int out_bf16)
{
  const int v0 = blockIdx.x * 64;
  __shared__ __align__(16) unsigned int As[2][64 * 64];  // 2 x 16 KB
  __shared__ int Pr[8 * 64];                             // 2 KB

  const int tid = threadIdx.x;
  const int wave = tid >> 6, lane = tid & 63;
  const int quad = lane >> 4, mr = lane & 15;
  const int lr0 = lane >> 4;       // row-in-4-group for staging
  const int j = lane & 15;         // dest 16B-chunk for staging

  for (int id = tid; id < 512; id += 256) {
    int r = id >> 6, d = id & 63;
    int v = v0 + d;
    Pr[id] = (v < NN) ? pidx[r * NN + v] : -1;
  }
  __syncthreads();                 // Pr ready for address calc

  // issue async stage of round r's 64x128 bf16 tile (rotated) into As[buf]
  auto ISSUE = [&](int r, int buf) {
#pragma unroll
    for (int i = 0; i < 4; ++i) {
      int d = wave * 16 + i * 4 + lr0;       // tile row; d & 15 == i*4+lr0
      int rot = i * 4 + lr0;
      int s = (j - rot) & 15;                // source chunk
      const unsigned int* base;
      if (r < 8) {
        int p = Pr[r * 64 + d];
        base = (p >= 0) ? (Agg + (size_t)p * 64) : Zrow;
      } else {
        int v = v0 + d;
        base = (v < NN) ? (Xin + (size_t)v * 64) : Zrow;
      }
      __builtin_amdgcn_global_load_lds(
          (const __attribute__((address_space(1))) unsigned int*)(base + s * 4),
          (__attribute__((address_space(3))) unsigned int*)
              &As[buf][(wave * 16 + i * 4) * 64],
          16, 0, 0);
    }
  };

  short8 bc0[4], bc1[4], bn0[4], bn1[4];
  auto LOADB = [&](int r, short8* d0, short8* d1) {
    const unsigned short* wr =
        Wt + (size_t)r * 16384 + (size_t)(wave * 32 + mr) * 128 + quad * 8;
#pragma unroll
    for (int ks = 0; ks < 4; ++ks) {
      d0[ks] = *(const short8*)(wr + ks * 32);
      d1[ks] = *(const short8*)(wr + 16 * 128 + ks * 32);
    }
  };

  floatx4 acc[4][2];
#pragma unroll
  for (int mi = 0; mi < 4; ++mi) {
    acc[mi][0] = (floatx4){0.f, 0.f, 0.f, 0.f};
    acc[mi][1] = (floatx4){0.f, 0.f, 0.f, 0.f};
  }

  // prologue: stage round 0, load B(0)
  ISSUE(0, 0);
  LOADB(0, bc0, bc1);
  __syncthreads();                 // vmcnt drain -> tile 0 in LDS

#pragma unroll 1
  for (int r = 0; r < 9; ++r) {
    if (r < 8) {
      ISSUE(r + 1, (r + 1) & 1);   // buffer free since barrier(end r-1)
      LOADB(r + 1, bn0, bn1);
    }
    const unsigned short* asb = (const unsigned short*)As[r & 1];
#pragma unroll
    for (int ks = 0; ks < 4; ++ks) {
      short8 a[4];
#pragma unroll
      for (int mi = 0; mi < 4; ++mi)
        a[mi] = *(const short8*)&asb[(mi * 16 + mr) * 128 +
                                     ((ks * 32 + quad * 8 + mr * 8) & 127)];
#pragma unroll
      for (int mi = 0; mi < 4; ++mi) {
        acc[mi][0] = __builtin_amdgcn_mfma_f32_16x16x32_bf16(a[mi], bc0[ks], acc[mi][0], 0, 0, 0);
        acc[mi][1] = __builtin_amdgcn_mfma_f32_16x16x32_bf16(a[mi], bc1[ks], acc[mi][1], 0, 0, 0);
      }
    }
    __syncthreads();               // drains vmcnt -> tile r+1 ready
#pragma unroll
    for (int ks = 0; ks < 4; ++ks) { bc0[ks] = bn0[ks]; bc1[ks] = bn1[ks]; }
  }

  // ---- epilogue: bias + ReLU, direct store ----
  float bia0 = bias[wave * 32 + mr], bia1 = bias[wave * 32 + 16 + mr];
#pragma unroll
  for (int mi = 0; mi < 4; ++mi)
#pragma unroll
    for (int rg = 0; rg < 4; ++rg) {
      int rw = mi * 16 + quad * 4 + rg;
      int v = v0 + rw;
      if (v < NN) {
        float c0 = fmaxf(acc[mi][0][rg] + bia0, 0.f);
        float c1 = fmaxf(acc[mi][1][rg] + bia1, 0.f);
        if (out_bf16) {
          ((unsigned int*)outp)[(size_t)v * 64 + wave * 16 + mr] = pk2bf(c0, c1);
        } else {
          float* o = (float*)outp;
          o[(size_t)v * 128 + wave * 32 + mr] = c0;
          o[(size_t)v * 128 + wave * 32 + 16 + mr] = c1;
        }
      }
    }
}

// ---------------------------------------------------------------------------
extern "C" void kernel_launch(void* const* d_in, const int* in_sizes, int n_in,
                              void* d_out, int out_size, void* d_ws, size_t ws_size,
                              hipStream_t stream) {
  const float* x       = (const float*)d_in[0];
  const int*   ei      = (const int*)d_in[1];
  const int*   et      = (const int*)d_in[2];
  const float* rel_w1  = (const float*)d_in[3];
  const float* root_w1 = (const float*)d_in[4];
  const float* b1      = (const float*)d_in[5];
  const float* rel_w2  = (const float*)d_in[6];
  const float* root_w2 = (const float*)d_in[7];
  const float* b2      = (const float*)d_in[8];

  char* ws = (char*)d_ws;
  size_t off = 0;
  auto alloc = [&](size_t bytes) { char* p = ws + off; off = (off + bytes + 255) & ~(size_t)255; return p; };
  unsigned int*   Xb    = (unsigned int*)alloc((size_t)NN * 64 * 4);         // 25.6 MB
  unsigned int*   h1    = (unsigned int*)alloc((size_t)NN * 64 * 4);         // 25.6 MB (permuted pack)
  unsigned int*   Agg   = (unsigned int*)alloc((size_t)EE * 64 * 4);         // 163.8 MB (worst case)
  unsigned short* Wt    = (unsigned short*)alloc((size_t)2 * 9 * DD * DD * 2);
  // ---- zero span: cnt + erowptr + Zrow ----
  int*            cnt   = (int*)alloc((size_t)K8 * 4);                       // 3.2 MB
  int*            erowptr = (int*)alloc((size_t)(EE + 2) * 4);               // 2.56 MB
  unsigned int*   Zrow  = (unsigned int*)alloc(256);                         // zero page
  char*           zend  = ws + off;
  // ---- rest ----
  int*            rowptr= (int*)alloc((size_t)(K8 + 1) * 4);                 // 3.2 MB
  int*            pidx  = (int*)alloc((size_t)K8 * 4);                       // 3.2 MB
  int*            erank = (int*)alloc((size_t)EE * 4);                       // 2.56 MB
  int*            recs  = (int*)alloc((size_t)EE * 4);                       // 2.56 MB
  int*            bsumA = (int*)alloc((size_t)NSB2 * 4);
  int*            bbaseA= (int*)alloc((size_t)NSB2 * 4);
  int*            bsumB = (int*)alloc((size_t)NSB2 * 4);
  int*            bbaseB= (int*)alloc((size_t)NSB2 * 4);
  int*            Ptot  = (int*)alloc(64);

  hipMemsetAsync(cnt, 0, (size_t)(zend - (char*)cnt), stream);

  xb_prep<<<(NN * 16) / 256, 256, 0, stream>>>(x, Xb);
  w_prep_all<<<(2 * 9 * DD * DD) / 256, 256, 0, stream>>>(rel_w1, root_w1, rel_w2, root_w2, Wt);
  count_all<<<EE / 256, 256, 0, stream>>>(ei, et, cnt, erank);

  // pass 1: rowptr (edge offsets per key)
  scan_a<<<NSB2, 256, 0, stream>>>((const int4*)cnt, K8 / 4, 0, bsumA);
  scan_b<<<1, 64, 0, stream>>>(bsumA, NSB2, bbaseA, nullptr);
  scan_c<<<NSB2, 256, 0, stream>>>(cnt, bbaseA, K8, 0, rowptr);

  // pass 2: rank compaction (pidx) + total rows
  scan_a<<<NSB2, 256, 0, stream>>>((const int4*)cnt, K8 / 4, 1, bsumB);
  scan_b<<<1, 64, 0, stream>>>(bsumB, NSB2, bbaseB, Ptot);
  scan_c<<<NSB2, 256, 0, stream>>>(cnt, bbaseB, K8, 1, pidx);

  erow_fill<<<K8 / 256, 256, 0, stream>>>(pidx, rowptr, Ptot, erowptr);
  place<<<EE / 256, 256, 0, stream>>>(ei, et, rowptr, erank, recs);

  agg_kernel<<<AGB, 256, 0, stream>>>(Xb, erowptr, recs, Agg);
  gemm_final<<<NB, 256, 0, stream>>>(Xb, Agg, Wt, pidx, Zrow, b1, h1, 1);
  agg_kernel<<<AGB, 256, 0, stream>>>(h1, erowptr, recs, Agg);
  gemm_final<<<NB, 256, 0, stream>>>(h1, Agg, Wt + (size_t)9 * DD * DD, pidx, Zrow, b2, d_out, 0);
}